// Round 5
// baseline (137.587 us; speedup 1.0000x reference)
//
#include <hip/hip_runtime.h>

// segment_sum: out[col_idx[i]] += values[i], out = float32[n_cols].
// Inputs: d_in[0]=row_idx (UNUSED), d_in[1]=col_idx (i32), d_in[2]=values (f32),
// d_in[3]=n_rows, d_in[4]=n_cols.
//
// Round-2 lesson: global f32 atomics write through 32B each at ~20G/s
// regardless of scope -> never use them. LDS-resident histograms only.
// Round-3 lesson: 2 loads in flight/thread -> ~980 cyc/iter latency-bound.
// This round: 4-deep explicit prefetch (8 loads in flight), R=4->3 passes
// (133.4 KB LDS/WG), B up to 85 chunks -> 255 blocks.

constexpr int R  = 3;       // column ranges (passes over the input)
constexpr int RS = 33336;   // columns per range (mult of 4); R*RS >= 100000
constexpr int BMAX = 85;    // max chunks per range -> B*R <= 255 blocks
#define TPB 1024

__device__ __forceinline__ void proc4(const int4& c, const float4& val,
                                      int base, float* hist) {
    unsigned d;
    d = (unsigned)(c.x - base); if (d < (unsigned)RS) atomicAdd(&hist[d], val.x);
    d = (unsigned)(c.y - base); if (d < (unsigned)RS) atomicAdd(&hist[d], val.y);
    d = (unsigned)(c.z - base); if (d < (unsigned)RS) atomicAdd(&hist[d], val.z);
    d = (unsigned)(c.w - base); if (d < (unsigned)RS) atomicAdd(&hist[d], val.w);
}

__global__ __launch_bounds__(TPB)
void scatter_lds_kernel(const int* __restrict__ col_idx,
                        const float* __restrict__ values,
                        float* __restrict__ ws,
                        int nnz, int B, int per) {
    __shared__ float hist[RS];

    const int b    = blockIdx.x;          // chunk index
    const int r    = blockIdx.y;          // range index
    const int base = r * RS;

    for (int i = threadIdx.x; i < RS; i += TPB) hist[i] = 0.0f;
    __syncthreads();

    const int nvec = nnz >> 2;
    const int v0   = b * per;
    const int v1   = min(nvec, v0 + per);

    const int4*   c4 = reinterpret_cast<const int4*>(col_idx);
    const float4* v4 = reinterpret_cast<const float4*>(values);

    int v = v0 + threadIdx.x;
    // 4-deep prefetch: issue all 8 loads (128 B/thread) before any atomic
    for (; v + 3 * TPB < v1; v += 4 * TPB) {
        int4   c0 = c4[v];
        int4   c1 = c4[v + TPB];
        int4   c2 = c4[v + 2 * TPB];
        int4   c3 = c4[v + 3 * TPB];
        float4 x0 = v4[v];
        float4 x1 = v4[v + TPB];
        float4 x2 = v4[v + 2 * TPB];
        float4 x3 = v4[v + 3 * TPB];
        proc4(c0, x0, base, hist);
        proc4(c1, x1, base, hist);
        proc4(c2, x2, base, hist);
        proc4(c3, x3, base, hist);
    }
    for (; v < v1; v += TPB) {
        int4 c = c4[v]; float4 x = v4[v];
        proc4(c, x, base, hist);
    }
    // tail elements (nnz % 4): last chunk's blocks handle them
    if (b == B - 1) {
        for (int i = (nvec << 2) + threadIdx.x; i < nnz; i += TPB) {
            unsigned d = (unsigned)(col_idx[i] - base);
            if (d < (unsigned)RS) atomicAdd(&hist[d], values[i]);
        }
    }
    __syncthreads();

    // dump histogram (coalesced float4) to ws copy (r*B + b)
    float4* dst = reinterpret_cast<float4*>(ws + (size_t)(r * B + b) * RS);
    const float4* src = reinterpret_cast<const float4*>(hist);
    for (int i = threadIdx.x; i < (RS >> 2); i += TPB) dst[i] = src[i];
}

__global__ void reduce_kernel(const float* __restrict__ ws,
                              float* __restrict__ out,
                              int ncols, int B) {
    int c = blockIdx.x * blockDim.x + threadIdx.x;
    if (c >= ncols) return;
    int r     = c / RS;
    int local = c - r * RS;
    const float* p = ws + (size_t)(r * B) * RS + local;
    float s = 0.0f;
    for (int b = 0; b < B; ++b) s += p[(size_t)b * RS];
    out[c] = s;
}

// ---- fallback (tiny ws / large ncols): direct device-scope atomics ----
__global__ void zero_out_kernel(float* __restrict__ out, int n) {
    int i = blockIdx.x * blockDim.x + threadIdx.x;
    if (i < n) out[i] = 0.0f;
}
__global__ void scatter_add_kernel(const int* __restrict__ col_idx,
                                   const float* __restrict__ values,
                                   float* __restrict__ out, int nnz) {
    const int tid    = blockIdx.x * blockDim.x + threadIdx.x;
    const int stride = gridDim.x * blockDim.x;
    const int nvec = nnz >> 2;
    const int4*   c4 = reinterpret_cast<const int4*>(col_idx);
    const float4* v4 = reinterpret_cast<const float4*>(values);
    for (int v = tid; v < nvec; v += stride) {
        int4 c = c4[v]; float4 x = v4[v];
        atomicAdd(&out[c.x], x.x); atomicAdd(&out[c.y], x.y);
        atomicAdd(&out[c.z], x.z); atomicAdd(&out[c.w], x.w);
    }
    for (int i = (nvec << 2) + tid; i < nnz; i += stride)
        atomicAdd(&out[col_idx[i]], values[i]);
}

extern "C" void kernel_launch(void* const* d_in, const int* in_sizes, int n_in,
                              void* d_out, int out_size, void* d_ws, size_t ws_size,
                              hipStream_t stream) {
    const int*   col_idx = (const int*)d_in[1];
    const float* values  = (const float*)d_in[2];
    float*       out     = (float*)d_out;
    const int    nnz     = in_sizes[1];
    const int    ncols   = out_size;

    // as many chunk-copies as ws allows, up to BMAX (grid = B*R <= 255)
    int B = (int)(ws_size / ((size_t)R * RS * sizeof(float)));
    if (B > BMAX) B = BMAX;

    if (ncols <= R * RS && B >= 4) {
        float* ws = (float*)d_ws;
        const int nvec = nnz >> 2;
        const int per  = (nvec + B - 1) / B;
        dim3 grid(B, R);
        scatter_lds_kernel<<<grid, TPB, 0, stream>>>(col_idx, values, ws,
                                                     nnz, B, per);
        int blocks = (ncols + 255) / 256;
        reduce_kernel<<<blocks, 256, 0, stream>>>(ws, out, ncols, B);
    } else {
        int blocks = (ncols + 255) / 256;
        zero_out_kernel<<<blocks, 256, 0, stream>>>(out, ncols);
        scatter_add_kernel<<<2048, 256, 0, stream>>>(col_idx, values, out, nnz);
    }
}

// Round 6
// 127.500 us; speedup vs baseline: 1.0791x; 1.0791x over previous
//
#include <hip/hip_runtime.h>

// segment_sum: out[col_idx[i]] += values[i], out = float32[n_cols].
// Inputs: d_in[0]=row_idx (UNUSED), d_in[1]=col_idx (i32), d_in[2]=values (f32),
// d_in[3]=n_rows, d_in[4]=n_cols.
//
// Lessons:
//  r2: global f32 atomics = 32B write-through @ ~20G/s regardless of scope.
//      Never use them. LDS-resident histograms only.
//  r5: replicas of a chunk MUST share an XCD (id%8). B=85 broke that ->
//      FETCH 78->234MB, effective BW 5.2->4.1 TB/s. Kernel is BW/queue-bound;
//      deeper per-thread ILP changed nothing (VGPR 52 both rounds).
//
// This round: 1-D grid, B=80 (mult of 8), r=id/B, b=id%B -> all 3 range-
// replicas of chunk b on XCD b%8; 2MB chunk fits 4MB L2 -> passes 2,3 hit L2.

constexpr int R  = 3;       // column ranges (passes over the input)
constexpr int RS = 33336;   // columns per range (mult of 8); R*RS >= 100000
constexpr int BMAX = 80;    // chunks; multiple of 8 so replicas share an XCD
#define TPB 1024

__device__ __forceinline__ void proc4(const int4& c, const float4& val,
                                      int base, float* hist) {
    unsigned d;
    d = (unsigned)(c.x - base); if (d < (unsigned)RS) atomicAdd(&hist[d], val.x);
    d = (unsigned)(c.y - base); if (d < (unsigned)RS) atomicAdd(&hist[d], val.y);
    d = (unsigned)(c.z - base); if (d < (unsigned)RS) atomicAdd(&hist[d], val.z);
    d = (unsigned)(c.w - base); if (d < (unsigned)RS) atomicAdd(&hist[d], val.w);
}

__global__ __launch_bounds__(TPB)
void scatter_lds_kernel(const int* __restrict__ col_idx,
                        const float* __restrict__ values,
                        float* __restrict__ ws,
                        int nnz, int B, int per) {
    __shared__ float hist[RS];

    const int id   = blockIdx.x;
    const int b    = id % B;              // chunk index  (replicas: same b,
    const int r    = id / B;              //  ids b, B+b, 2B+b -> same id%8 XCD)
    const int base = r * RS;

    for (int i = threadIdx.x; i < RS; i += TPB) hist[i] = 0.0f;
    __syncthreads();

    const int nvec = nnz >> 2;
    const int v0   = b * per;
    const int v1   = min(nvec, v0 + per);

    const int4*   c4 = reinterpret_cast<const int4*>(col_idx);
    const float4* v4 = reinterpret_cast<const float4*>(values);

    int v = v0 + threadIdx.x;
    // 4-deep prefetch main loop (8 loads issued before any LDS atomic)
    for (; v + 3 * TPB < v1; v += 4 * TPB) {
        int4   c0 = c4[v];
        int4   c1 = c4[v + TPB];
        int4   c2 = c4[v + 2 * TPB];
        int4   c3 = c4[v + 3 * TPB];
        float4 x0 = v4[v];
        float4 x1 = v4[v + TPB];
        float4 x2 = v4[v + 2 * TPB];
        float4 x3 = v4[v + 3 * TPB];
        proc4(c0, x0, base, hist);
        proc4(c1, x1, base, hist);
        proc4(c2, x2, base, hist);
        proc4(c3, x3, base, hist);
    }
    // cleanup with distance-1 rolling prefetch
    if (v < v1) {
        int4 cc = c4[v]; float4 xx = v4[v];
        for (v += TPB; v < v1; v += TPB) {
            int4 cn = c4[v]; float4 xn = v4[v];
            proc4(cc, xx, base, hist);
            cc = cn; xx = xn;
        }
        proc4(cc, xx, base, hist);
    }
    // tail elements (nnz % 4): last chunk's blocks handle them
    if (b == B - 1) {
        for (int i = (nvec << 2) + threadIdx.x; i < nnz; i += TPB) {
            unsigned d = (unsigned)(col_idx[i] - base);
            if (d < (unsigned)RS) atomicAdd(&hist[d], values[i]);
        }
    }
    __syncthreads();

    // dump histogram (coalesced float4) to ws copy (r*B + b)
    float4* dst = reinterpret_cast<float4*>(ws + (size_t)(r * B + b) * RS);
    const float4* src = reinterpret_cast<const float4*>(hist);
    for (int i = threadIdx.x; i < (RS >> 2); i += TPB) dst[i] = src[i];
}

__global__ void reduce_kernel(const float* __restrict__ ws,
                              float* __restrict__ out,
                              int ncols, int B) {
    int c = blockIdx.x * blockDim.x + threadIdx.x;
    if (c >= ncols) return;
    int r     = c / RS;
    int local = c - r * RS;
    const float* p = ws + (size_t)(r * B) * RS + local;
    float s = 0.0f;
#pragma unroll 8
    for (int b = 0; b < B; ++b) s += p[(size_t)b * RS];
    out[c] = s;
}

// ---- fallback (tiny ws / large ncols): direct device-scope atomics ----
__global__ void zero_out_kernel(float* __restrict__ out, int n) {
    int i = blockIdx.x * blockDim.x + threadIdx.x;
    if (i < n) out[i] = 0.0f;
}
__global__ void scatter_add_kernel(const int* __restrict__ col_idx,
                                   const float* __restrict__ values,
                                   float* __restrict__ out, int nnz) {
    const int tid    = blockIdx.x * blockDim.x + threadIdx.x;
    const int stride = gridDim.x * blockDim.x;
    const int nvec = nnz >> 2;
    const int4*   c4 = reinterpret_cast<const int4*>(col_idx);
    const float4* v4 = reinterpret_cast<const float4*>(values);
    for (int v = tid; v < nvec; v += stride) {
        int4 c = c4[v]; float4 x = v4[v];
        atomicAdd(&out[c.x], x.x); atomicAdd(&out[c.y], x.y);
        atomicAdd(&out[c.z], x.z); atomicAdd(&out[c.w], x.w);
    }
    for (int i = (nvec << 2) + tid; i < nnz; i += stride)
        atomicAdd(&out[col_idx[i]], values[i]);
}

extern "C" void kernel_launch(void* const* d_in, const int* in_sizes, int n_in,
                              void* d_out, int out_size, void* d_ws, size_t ws_size,
                              hipStream_t stream) {
    const int*   col_idx = (const int*)d_in[1];
    const float* values  = (const float*)d_in[2];
    float*       out     = (float*)d_out;
    const int    nnz     = in_sizes[1];
    const int    ncols   = out_size;

    // chunks: multiple of 8 (XCD alignment), as many as ws allows up to BMAX
    int B = (int)(ws_size / ((size_t)R * RS * sizeof(float)));
    if (B > BMAX) B = BMAX;
    B &= ~7;  // round down to multiple of 8

    if (ncols <= R * RS && B >= 8) {
        float* ws = (float*)d_ws;
        const int nvec = nnz >> 2;
        const int per  = (nvec + B - 1) / B;
        scatter_lds_kernel<<<B * R, TPB, 0, stream>>>(col_idx, values, ws,
                                                      nnz, B, per);
        int blocks = (ncols + 255) / 256;
        reduce_kernel<<<blocks, 256, 0, stream>>>(ws, out, ncols, B);
    } else {
        int blocks = (ncols + 255) / 256;
        zero_out_kernel<<<blocks, 256, 0, stream>>>(out, ncols);
        scatter_add_kernel<<<2048, 256, 0, stream>>>(col_idx, values, out, nnz);
    }
}